// Round 5
// baseline (375.764 us; speedup 1.0000x reference)
//
#include <hip/hip_runtime.h>

#define HW 2304          // 48*48
#define NB 8             // batch
#define NC 256           // input channels
#define HID 128          // heads*dim_head
#define DH 32            // dim_head
#define NH 4             // heads
#define SCALE 0.17677669529663687f  // 1/sqrt(32)

using bf16x8 = __attribute__((ext_vector_type(8))) short;
using f32x4  = __attribute__((ext_vector_type(4))) float;

__device__ __forceinline__ short f2bf(float f) {   // RNE float->bf16
    unsigned u = __float_as_uint(f);
    u += 0x7FFF + ((u >> 16) & 1);
    return (short)(u >> 16);
}

// ---------------------------------------------------------------------------
// Pre-pass: fp32 weights -> bf16 (row-major unchanged).
// ---------------------------------------------------------------------------
__global__ void cvt_w(const float* __restrict__ wq, const float* __restrict__ wo,
                      short* __restrict__ Wq, short* __restrict__ Wo)
{
    const int i = blockIdx.x * 256 + threadIdx.x;
    if (i < 384 * 256) Wq[i] = f2bf(wq[i]);
    if (i < 256 * 128) Wo[i] = f2bf(wo[i]);
}

// ---------------------------------------------------------------------------
// Pre-pass: x [b][256][2304] fp32 -> Xt [b][2304][256] bf16 (LDS transpose).
// ---------------------------------------------------------------------------
__global__ __launch_bounds__(256)
void xpose_cvt(const float* __restrict__ x, short* __restrict__ Xt)
{
    __shared__ float T[32][33];
    const int b = blockIdx.z, c0 = blockIdx.y * 32, s0 = blockIdx.x * 32;
    const int ts = threadIdx.x & 31, tc = threadIdx.x >> 5;
    #pragma unroll
    for (int cc = tc; cc < 32; cc += 8)
        T[cc][ts] = x[((size_t)b * NC + c0 + cc) * HW + s0 + ts];
    __syncthreads();
    const int tcc = threadIdx.x & 31, tss = threadIdx.x >> 5;
    #pragma unroll
    for (int ss = tss; ss < 32; ss += 8)
        Xt[((size_t)b * HW + s0 + ss) * NC + c0 + tcc] = f2bf(T[tcc][ss]);
}

// ---------------------------------------------------------------------------
// MFMA 1x1-conv GEMM: C[o][s] = sum_c A[o][c] * Bt[s][c], tile M64 x N128,
// K-chunks of 32, 4 waves. Wave w: A-subtile w staged by itself; owns n-tiles
// {2w,2w+1} x all 4 m-tiles -> 8 MFMA per chunk. LDS layout per subtile:
// lane L=(kchunk<<4)|row deposits 16B, frag read = own deposit slot.
// QKV=true: epilogue -> bf16 Q(xSCALE)/K [bh][s][dh] (packed short4), V [bh][dh][s].
// QKV=false: fp32 out + ticketed final energy store.
// ---------------------------------------------------------------------------
template<int KD, bool QKV>
__global__ __launch_bounds__(256, 4)
void conv_mfma(const short* __restrict__ A, const short* __restrict__ Bt,
               const float* __restrict__ bias, float* __restrict__ out0,
               short* __restrict__ Qb, short* __restrict__ Kb,
               short* __restrict__ Vb, float* __restrict__ E,
               int* __restrict__ ticket, int nblocks, float* __restrict__ edst)
{
    const int b  = blockIdx.z;
    const int bm = blockIdx.y * 64;
    const int bn = blockIdx.x * 128;
    const int t  = threadIdx.x;
    const int w  = t >> 6, lane = t & 63;
    const int n16 = lane & 15, quad = lane >> 4;

    __shared__ short As[4 * 512];    // 4 subtiles x (16 rows x 4 kchunks x 8)
    __shared__ short Bs[8 * 512];
    __shared__ float red[4];

    const int Lrow = lane & 15, Lch = lane >> 4;
    const short* Ag  = A  + (size_t)(bm + w * 16 + Lrow) * KD + Lch * 8;
    const short* Bg0 = Bt + ((size_t)b * HW + bn + (w * 2 + 0) * 16 + Lrow) * KD + Lch * 8;
    const short* Bg1 = Bt + ((size_t)b * HW + bn + (w * 2 + 1) * 16 + Lrow) * KD + Lch * 8;

    f32x4 acc[4][2] = {};

    for (int kc = 0; kc < KD; kc += 32) {
        const bf16x8 va  = *(const bf16x8*)(Ag + kc);
        const bf16x8 vb0 = *(const bf16x8*)(Bg0 + kc);
        const bf16x8 vb1 = *(const bf16x8*)(Bg1 + kc);
        *(bf16x8*)(As + w * 512 + lane * 8)           = va;
        *(bf16x8*)(Bs + (w * 2 + 0) * 512 + lane * 8) = vb0;
        *(bf16x8*)(Bs + (w * 2 + 1) * 512 + lane * 8) = vb1;
        __syncthreads();

        bf16x8 am[4], bq[2];
        #pragma unroll
        for (int tm = 0; tm < 4; ++tm)
            am[tm] = *(const bf16x8*)(As + tm * 512 + (quad * 16 + n16) * 8);
        #pragma unroll
        for (int j = 0; j < 2; ++j)
            bq[j] = *(const bf16x8*)(Bs + (w * 2 + j) * 512 + (quad * 16 + n16) * 8);
        #pragma unroll
        for (int tm = 0; tm < 4; ++tm)
            #pragma unroll
            for (int j = 0; j < 2; ++j)
                acc[tm][j] = __builtin_amdgcn_mfma_f32_16x16x32_bf16(am[tm], bq[j], acc[tm][j], 0, 0, 0);
        __syncthreads();
    }

    float e = 0.f;
    #pragma unroll
    for (int tm = 0; tm < 4; ++tm) {
        const int o0 = bm + tm * 16 + quad * 4;
        const float4 bb = *(const float4*)(bias + o0);
        #pragma unroll
        for (int j = 0; j < 2; ++j) {
            const int s = bn + (w * 2 + j) * 16 + n16;
            float v[4] = {acc[tm][j][0] + bb.x, acc[tm][j][1] + bb.y,
                          acc[tm][j][2] + bb.z, acc[tm][j][3] + bb.w};
            e -= 0.5f * (v[0]*v[0] + v[1]*v[1] + v[2]*v[2] + v[3]*v[3]);
            if (QKV) {
                if (o0 < HID) {                       // Q: scaled, packed short4
                    const int h = o0 >> 5, dh0 = o0 & 31;
                    short4 pk = {f2bf(v[0]*SCALE), f2bf(v[1]*SCALE),
                                 f2bf(v[2]*SCALE), f2bf(v[3]*SCALE)};
                    *(short4*)(Qb + ((size_t)(b * NH + h) * HW + s) * DH + dh0) = pk;
                } else if (o0 < 2 * HID) {            // K
                    const int c = o0 - HID, h = c >> 5, dh0 = c & 31;
                    short4 pk = {f2bf(v[0]), f2bf(v[1]), f2bf(v[2]), f2bf(v[3])};
                    *(short4*)(Kb + ((size_t)(b * NH + h) * HW + s) * DH + dh0) = pk;
                } else {                              // V: [bh][dh][s]
                    const int c = o0 - 2 * HID, h = c >> 5, dh0 = c & 31;
                    #pragma unroll
                    for (int r = 0; r < 4; ++r)
                        Vb[((size_t)(b * NH + h) * DH + dh0 + r) * HW + s] = f2bf(v[r]);
                }
            } else {
                #pragma unroll
                for (int r = 0; r < 4; ++r)
                    out0[((size_t)b * NC + o0 + r) * HW + s] = v[r];
            }
        }
    }

    #pragma unroll
    for (int off = 32; off > 0; off >>= 1) e += __shfl_down(e, off);
    if (lane == 0) red[w] = e;
    __syncthreads();
    if (t == 0) {
        atomicAdd(E, red[0] + red[1] + red[2] + red[3]);
        if (!QKV) {                                   // ticketed final energy store
            __threadfence();
            const int prev = atomicAdd(ticket, 1);
            if (prev == nblocks - 1) {
                __threadfence();
                edst[0] = atomicAdd(E, 0.f);          // atomic read-current
            }
        }
    }
}

// ---------------------------------------------------------------------------
// Flash attention, MFMA. Block = 4 waves: wave (qsub, khalf) owns 16 queries
// (qsub) and half the keys (khalf). m=0 fixed shift => key-split merge is a
// pure add (LDS). Keys paired (2*n16, 2*n16+1) so P stores are 4x b32;
// P double-buffered to break the WAR chain. Writes attT bf16 [b][s][hid].
// ---------------------------------------------------------------------------
__global__ __launch_bounds__(256, 8)
void flash2(const short* __restrict__ Qb, const short* __restrict__ Kb,
            const short* __restrict__ Vb, short* __restrict__ attT,
            float* __restrict__ E)
{
    const int bh   = blockIdx.y;
    const int w    = threadIdx.x >> 6;
    const int lane = threadIdx.x & 63;
    const int qsub = w & 1, khalf = w >> 1;
    const int n16  = lane & 15, quad = lane >> 4;
    const int qb   = blockIdx.x * 32 + qsub * 16;

    __shared__ short P[4][2][16 * 40];   // per-wave double-buffered P tile
    __shared__ float M[2][64][17];       // key-split merge buffer

    const bf16x8 aq = *(const bf16x8*)(Qb + ((size_t)bh * HW + qb + n16) * DH + quad * 8);
    const short* kp = Kb + (size_t)bh * HW * DH;
    const short* vp = Vb + (size_t)bh * DH * HW;

    f32x4 acc0 = {}, acc1 = {};
    float ls[4] = {}, ts[4] = {};

    const int j0 = khalf * (HW / 2), j1 = j0 + HW / 2;
    int buf = 0;
    for (int c0 = j0; c0 < j1; c0 += 32) {
        const bf16x8 bk0 = *(const bf16x8*)(kp + (size_t)(c0 + 2 * n16) * DH + quad * 8);
        const bf16x8 bk1 = *(const bf16x8*)(kp + (size_t)(c0 + 2 * n16 + 1) * DH + quad * 8);
        const bf16x8 bv0 = *(const bf16x8*)(vp + (size_t)n16 * HW + c0 + quad * 8);
        const bf16x8 bv1 = *(const bf16x8*)(vp + (size_t)(n16 + 16) * HW + c0 + quad * 8);

        f32x4 z = {};
        const f32x4 s0 = __builtin_amdgcn_mfma_f32_16x16x32_bf16(aq, bk0, z, 0, 0, 0);
        const f32x4 s1 = __builtin_amdgcn_mfma_f32_16x16x32_bf16(aq, bk1, z, 0, 0, 0);

        short* Pb = &P[w][buf][0];
        unsigned* Pb32 = (unsigned*)Pb;
        #pragma unroll
        for (int r = 0; r < 4; ++r) {
            const float p0 = __expf(s0[r]);
            const float p1 = __expf(s1[r]);
            ls[r] += p0 + p1;
            ts[r] += p0 * s0[r] + p1 * s1[r];
            Pb32[(quad * 4 + r) * 20 + n16] =
                (unsigned)(unsigned short)f2bf(p0) |
                ((unsigned)(unsigned short)f2bf(p1) << 16);
        }
        const bf16x8 pa = *(const bf16x8*)(Pb + n16 * 40 + quad * 8);
        acc0 = __builtin_amdgcn_mfma_f32_16x16x32_bf16(pa, bv0, acc0, 0, 0, 0);
        acc1 = __builtin_amdgcn_mfma_f32_16x16x32_bf16(pa, bv1, acc1, 0, 0, 0);
        buf ^= 1;
    }

    if (khalf == 1) {            // publish partials for merge (m=0: pure add)
        float* mp = M[qsub][lane];
        #pragma unroll
        for (int r = 0; r < 4; ++r) {
            mp[r] = ls[r]; mp[4 + r] = ts[r];
            mp[8 + r] = acc0[r]; mp[12 + r] = acc1[r];
        }
    }
    __syncthreads();
    if (khalf == 0) {
        const float* mp = M[qsub][lane];
        #pragma unroll
        for (int r = 0; r < 4; ++r) {
            ls[r] += mp[r]; ts[r] += mp[4 + r];
            acc0[r] += mp[8 + r]; acc1[r] += mp[12 + r];
        }
        #pragma unroll
        for (int m = 1; m < 16; m <<= 1) {
            #pragma unroll
            for (int r = 0; r < 4; ++r) {
                ls[r] += __shfl_xor(ls[r], m);
                ts[r] += __shfl_xor(ts[r], m);
            }
        }
        const int bb = bh >> 2, h = bh & 3;
        float e = 0.f;
        #pragma unroll
        for (int r = 0; r < 4; ++r) {
            const int q = qb + quad * 4 + r;
            const float invl = 1.f / ls[r];
            short* ap = attT + ((size_t)bb * HW + q) * HID + h * 32;
            ap[n16]      = f2bf(acc0[r] * invl);
            ap[n16 + 16] = f2bf(acc1[r] * invl);
            e += ts[r] * invl - __logf(ls[r]);
        }
        e = (n16 == 0) ? e : 0.f;
        e += __shfl_xor(e, 16);
        e += __shfl_xor(e, 32);
        if (lane == 0) atomicAdd(E, e);
    }
}

// ---------------------------------------------------------------------------
extern "C" void kernel_launch(void* const* d_in, const int* in_sizes, int n_in,
                              void* d_out, int out_size, void* d_ws, size_t ws_size,
                              hipStream_t stream) {
    const float* x     = (const float*)d_in[0];
    const float* w_qkv = (const float*)d_in[1];
    const float* b_qkv = (const float*)d_in[2];
    const float* w_out = (const float*)d_in[3];
    const float* b_out = (const float*)d_in[4];
    float* out = (float*)d_out;

    float* wsf    = (float*)d_ws;
    float* E      = wsf;                               // [0] energy accumulator
    int*   ticket = (int*)d_ws + 1;                    // [1] conv2 completion ticket
    short* Xt   = (short*)(wsf + 16);                  // bf16 [b][s][c]     9.44 MB
    short* Wq   = Xt + (size_t)NB * HW * NC;           // bf16 [384][256]
    short* Wo   = Wq + 384 * 256;                      // bf16 [256][128]
    short* Qb   = Wo + 256 * 128;                      // bf16 [bh][s][dh] (xSCALE)
    short* Kb   = Qb + (size_t)NB * NH * HW * DH;      // bf16 [bh][s][dh]
    short* Vb   = Kb + (size_t)NB * NH * HW * DH;      // bf16 [bh][dh][s]
    short* attT = Vb + (size_t)NB * NH * HW * DH;      // bf16 [b][s][hid]

    (void)hipMemsetAsync(d_ws, 0, 64, stream);         // zero E + ticket

    cvt_w<<<384, 256, 0, stream>>>(w_qkv, w_out, Wq, Wo);
    xpose_cvt<<<dim3(HW / 32, NC / 32, NB), 256, 0, stream>>>(x, Xt);
    conv_mfma<NC, true><<<dim3(18, 6, NB), 256, 0, stream>>>(
        Wq, Xt, b_qkv, nullptr, Qb, Kb, Vb, E, nullptr, 0, nullptr);
    flash2<<<dim3(HW / 32, NB * NH), 256, 0, stream>>>(Qb, Kb, Vb, attT, E);
    conv_mfma<HID, false><<<dim3(18, 4, NB), 256, 0, stream>>>(
        Wo, attT, b_out, out, nullptr, nullptr, nullptr, E,
        ticket, 18 * 4 * NB, out + (size_t)NB * NC * HW);
}

// Round 6
// 304.884 us; speedup vs baseline: 1.2325x; 1.2325x over previous
//
#include <hip/hip_runtime.h>
#include <hip/hip_bf16.h>

#define HW 2304          // 48*48
#define NB 8             // batch
#define NC 256           // input channels
#define HID 128          // heads*dim_head
#define DH 32            // dim_head
#define NH 4             // heads
#define SCALE 0.17677669529663687f  // 1/sqrt(32)

using bf16x8 = __attribute__((ext_vector_type(8))) short;
using f32x4  = __attribute__((ext_vector_type(4))) float;

__device__ __forceinline__ short f2bf(float f) {   // RNE float->bf16
    unsigned u = __float_as_uint(f);
    u += 0x7FFF + ((u >> 16) & 1);
    return (short)(u >> 16);
}
__device__ __forceinline__ unsigned pk2bf(float a, float b) {  // pack 2 bf16 (RNE)
    union { __hip_bfloat162 h; unsigned u; } cv;
    cv.h = __float22bfloat162_rn(float2{a, b});
    return cv.u;
}

// ---------------------------------------------------------------------------
// Pre-pass: fp32 weights -> bf16.
// ---------------------------------------------------------------------------
__global__ void cvt_w(const float* __restrict__ wq, const float* __restrict__ wo,
                      short* __restrict__ Wq, short* __restrict__ Wo)
{
    const int i = blockIdx.x * 256 + threadIdx.x;
    if (i < 384 * 256) Wq[i] = f2bf(wq[i]);
    if (i < 256 * 128) Wo[i] = f2bf(wo[i]);
}

// ---------------------------------------------------------------------------
// Pre-pass: x [b][256][2304] fp32 -> Xt [b][2304][256] bf16 (LDS transpose).
// ---------------------------------------------------------------------------
__global__ __launch_bounds__(256)
void xpose_cvt(const float* __restrict__ x, short* __restrict__ Xt)
{
    __shared__ float T[32][33];
    const int b = blockIdx.z, c0 = blockIdx.y * 32, s0 = blockIdx.x * 32;
    const int ts = threadIdx.x & 31, tc = threadIdx.x >> 5;
    #pragma unroll
    for (int cc = tc; cc < 32; cc += 8)
        T[cc][ts] = x[((size_t)b * NC + c0 + cc) * HW + s0 + ts];
    __syncthreads();
    const int tcc = threadIdx.x & 31, tss = threadIdx.x >> 5;
    #pragma unroll
    for (int ss = tss; ss < 32; ss += 8)
        Xt[((size_t)b * HW + s0 + ss) * NC + c0 + tcc] = f2bf(T[tcc][ss]);
}

// ---------------------------------------------------------------------------
// LDS-free MFMA 1x1-conv GEMM: C[o][s] = sum_c A[o][c]*Bt[s][c].
// Tile M64 x N128, 4 waves; wave w owns n-tiles {2w,2w+1} x 4 m-tiles.
// A (weights, L2-resident) and B frags load straight global->VGPR; no
// barriers in the K-loop so the compiler pipelines freely.
// QKV epilogue: Q(xSCALE)/K bf16 [bh][s][dh] (K pair-permuted within each
// 32-key group: pos p<16 <-> key 2p, p>=16 <-> key 2(p-16)+1), V [bh][dh][s].
// else: fp32 out + ticketed final energy store.
// ---------------------------------------------------------------------------
template<int KD, bool QKV>
__global__ __launch_bounds__(256, 4)
void conv_mfma(const short* __restrict__ A, const short* __restrict__ Bt,
               const float* __restrict__ bias, float* __restrict__ out0,
               short* __restrict__ Qb, short* __restrict__ Kb,
               short* __restrict__ Vb, float* __restrict__ E,
               int* __restrict__ ticket, int nblocks, float* __restrict__ edst)
{
    const int b  = blockIdx.z;
    const int bm = blockIdx.y * 64;
    const int bn = blockIdx.x * 128;
    const int t  = threadIdx.x;
    const int w  = t >> 6, lane = t & 63;
    const int n16 = lane & 15, quad = lane >> 4;

    __shared__ float red[4];

    const short* Ag  = A + (size_t)(bm + n16) * KD + quad * 8;              // m-tile 0
    const short* Bg0 = Bt + ((size_t)b * HW + bn + (w * 2 + 0) * 16 + n16) * KD + quad * 8;
    const short* Bg1 = Bt + ((size_t)b * HW + bn + (w * 2 + 1) * 16 + n16) * KD + quad * 8;

    f32x4 acc[4][2] = {};

    for (int kc = 0; kc < KD; kc += 32) {
        bf16x8 am[4], bq[2];
        #pragma unroll
        for (int tm = 0; tm < 4; ++tm)
            am[tm] = *(const bf16x8*)(Ag + (size_t)tm * 16 * KD + kc);
        bq[0] = *(const bf16x8*)(Bg0 + kc);
        bq[1] = *(const bf16x8*)(Bg1 + kc);
        #pragma unroll
        for (int tm = 0; tm < 4; ++tm)
            #pragma unroll
            for (int j = 0; j < 2; ++j)
                acc[tm][j] = __builtin_amdgcn_mfma_f32_16x16x32_bf16(am[tm], bq[j], acc[tm][j], 0, 0, 0);
    }

    float e = 0.f;
    #pragma unroll
    for (int tm = 0; tm < 4; ++tm) {
        const int o0 = bm + tm * 16 + quad * 4;
        const float4 bb = *(const float4*)(bias + o0);
        #pragma unroll
        for (int j = 0; j < 2; ++j) {
            const int s = bn + (w * 2 + j) * 16 + n16;
            float v[4] = {acc[tm][j][0] + bb.x, acc[tm][j][1] + bb.y,
                          acc[tm][j][2] + bb.z, acc[tm][j][3] + bb.w};
            e -= 0.5f * (v[0]*v[0] + v[1]*v[1] + v[2]*v[2] + v[3]*v[3]);
            if (QKV) {
                if (o0 < HID) {                       // Q: scaled
                    const int h = o0 >> 5, dh0 = o0 & 31;
                    short4 pk = {f2bf(v[0]*SCALE), f2bf(v[1]*SCALE),
                                 f2bf(v[2]*SCALE), f2bf(v[3]*SCALE)};
                    *(short4*)(Qb + ((size_t)(b * NH + h) * HW + s) * DH + dh0) = pk;
                } else if (o0 < 2 * HID) {            // K: pair-permuted rows
                    const int c = o0 - HID, h = c >> 5, dh0 = c & 31;
                    const int g = s & 31;
                    const int sp = (s & ~31) | ((g & 1) << 4) | (g >> 1);
                    short4 pk = {f2bf(v[0]), f2bf(v[1]), f2bf(v[2]), f2bf(v[3])};
                    *(short4*)(Kb + ((size_t)(b * NH + h) * HW + sp) * DH + dh0) = pk;
                } else {                              // V: [bh][dh][s]
                    const int c = o0 - 2 * HID, h = c >> 5, dh0 = c & 31;
                    #pragma unroll
                    for (int r = 0; r < 4; ++r)
                        Vb[((size_t)(b * NH + h) * DH + dh0 + r) * HW + s] = f2bf(v[r]);
                }
            } else {
                #pragma unroll
                for (int r = 0; r < 4; ++r)
                    out0[((size_t)b * NC + o0 + r) * HW + s] = v[r];
            }
        }
    }

    #pragma unroll
    for (int off = 32; off > 0; off >>= 1) e += __shfl_down(e, off);
    if (lane == 0) red[w] = e;
    __syncthreads();
    if (t == 0) {
        atomicAdd(E, red[0] + red[1] + red[2] + red[3]);
        if (!QKV) {
            __threadfence();
            const int prev = atomicAdd(ticket, 1);
            if (prev == nblocks - 1) {
                __threadfence();
                edst[0] = atomicAdd(E, 0.f);
            }
        }
    }
}

// ---------------------------------------------------------------------------
// Flash attention (round-4 structure + pipeline). 4 waves x 16 queries; each
// wave walks all 2304 keys in chunks of 32, software-pipelined one chunk
// ahead. K rows are pair-permuted, so P(exp scores) packs into 4x b32 LDS
// stores at natural key columns; PV reads V in natural order. m=0 fixed
// shift (|s|<~1; energy is shift-invariant). attT out: bf16 [b][s][hid].
// ---------------------------------------------------------------------------
__global__ __launch_bounds__(256)
void flash3(const short* __restrict__ Qb, const short* __restrict__ Kb,
            const short* __restrict__ Vb, short* __restrict__ attT,
            float* __restrict__ E)
{
    const int bh   = blockIdx.y;
    const int w    = threadIdx.x >> 6;
    const int lane = threadIdx.x & 63;
    const int n16  = lane & 15, quad = lane >> 4;
    const int qb   = blockIdx.x * 64 + w * 16;

    __shared__ short P[4][16 * 40];     // per-wave P tile, stride 40 shorts

    const bf16x8 aq = *(const bf16x8*)(Qb + ((size_t)bh * HW + qb + n16) * DH + quad * 8);
    const short* kp = Kb + (size_t)bh * HW * DH;
    const short* vp = Vb + (size_t)bh * DH * HW;

    f32x4 acc0 = {}, acc1 = {};
    float ls[4] = {}, ts[4] = {};

    short* Pw = &P[w][0];
    unsigned* Pw32 = (unsigned*)Pw;

    // prefetch chunk 0
    bf16x8 bk0 = *(const bf16x8*)(kp + (size_t)n16 * DH + quad * 8);
    bf16x8 bk1 = *(const bf16x8*)(kp + (size_t)(16 + n16) * DH + quad * 8);
    bf16x8 bv0 = *(const bf16x8*)(vp + (size_t)n16 * HW + quad * 8);
    bf16x8 bv1 = *(const bf16x8*)(vp + (size_t)(n16 + 16) * HW + quad * 8);

    for (int c0 = 0; c0 < HW; c0 += 32) {
        const int cn = (c0 + 32 < HW) ? c0 + 32 : 0;    // wrap: loaded, unused
        const bf16x8 nk0 = *(const bf16x8*)(kp + (size_t)(cn + n16) * DH + quad * 8);
        const bf16x8 nk1 = *(const bf16x8*)(kp + (size_t)(cn + 16 + n16) * DH + quad * 8);
        const bf16x8 nv0 = *(const bf16x8*)(vp + (size_t)n16 * HW + cn + quad * 8);
        const bf16x8 nv1 = *(const bf16x8*)(vp + (size_t)(n16 + 16) * HW + cn + quad * 8);

        f32x4 z = {};
        const f32x4 s0 = __builtin_amdgcn_mfma_f32_16x16x32_bf16(aq, bk0, z, 0, 0, 0);
        const f32x4 s1 = __builtin_amdgcn_mfma_f32_16x16x32_bf16(aq, bk1, z, 0, 0, 0);

        // s0[r] = key 2*n16, s1[r] = key 2*n16+1 (pair-permuted K rows)
        #pragma unroll
        for (int r = 0; r < 4; ++r) {
            const float p0 = __expf(s0[r]);
            const float p1 = __expf(s1[r]);
            ls[r] += p0 + p1;
            ts[r] += p0 * s0[r] + p1 * s1[r];
            Pw32[(quad * 4 + r) * 20 + n16] = pk2bf(p0, p1);
        }
        const bf16x8 pa = *(const bf16x8*)(Pw + n16 * 40 + quad * 8);
        acc0 = __builtin_amdgcn_mfma_f32_16x16x32_bf16(pa, bv0, acc0, 0, 0, 0);
        acc1 = __builtin_amdgcn_mfma_f32_16x16x32_bf16(pa, bv1, acc1, 0, 0, 0);

        bk0 = nk0; bk1 = nk1; bv0 = nv0; bv1 = nv1;
    }

    #pragma unroll
    for (int m = 1; m < 16; m <<= 1) {
        #pragma unroll
        for (int r = 0; r < 4; ++r) {
            ls[r] += __shfl_xor(ls[r], m);
            ts[r] += __shfl_xor(ts[r], m);
        }
    }

    const int bb = bh >> 2, h = bh & 3;
    float e = 0.f;
    #pragma unroll
    for (int r = 0; r < 4; ++r) {
        const int q = qb + quad * 4 + r;
        const float invl = 1.f / ls[r];
        short* ap = attT + ((size_t)bb * HW + q) * HID + h * 32;
        ap[n16]      = f2bf(acc0[r] * invl);
        ap[n16 + 16] = f2bf(acc1[r] * invl);
        e += ts[r] * invl - __logf(ls[r]);
    }
    e = (n16 == 0) ? e : 0.f;
    e += __shfl_xor(e, 16);
    e += __shfl_xor(e, 32);
    if (lane == 0) atomicAdd(E, e);
}

// ---------------------------------------------------------------------------
extern "C" void kernel_launch(void* const* d_in, const int* in_sizes, int n_in,
                              void* d_out, int out_size, void* d_ws, size_t ws_size,
                              hipStream_t stream) {
    const float* x     = (const float*)d_in[0];
    const float* w_qkv = (const float*)d_in[1];
    const float* b_qkv = (const float*)d_in[2];
    const float* w_out = (const float*)d_in[3];
    const float* b_out = (const float*)d_in[4];
    float* out = (float*)d_out;

    float* wsf    = (float*)d_ws;
    float* E      = wsf;                               // [0] energy accumulator
    int*   ticket = (int*)d_ws + 1;                    // [1] conv2 ticket
    short* Xt   = (short*)(wsf + 16);                  // bf16 [b][s][c]
    short* Wq   = Xt + (size_t)NB * HW * NC;           // bf16 [384][256]
    short* Wo   = Wq + 384 * 256;                      // bf16 [256][128]
    short* Qb   = Wo + 256 * 128;                      // bf16 [bh][s][dh] (xSCALE)
    short* Kb   = Qb + (size_t)NB * NH * HW * DH;      // bf16 [bh][s'][dh], pair-permuted
    short* Vb   = Kb + (size_t)NB * NH * HW * DH;      // bf16 [bh][dh][s]
    short* attT = Vb + (size_t)NB * NH * HW * DH;      // bf16 [b][s][hid]

    (void)hipMemsetAsync(d_ws, 0, 64, stream);

    cvt_w<<<384, 256, 0, stream>>>(w_qkv, w_out, Wq, Wo);
    xpose_cvt<<<dim3(HW / 32, NC / 32, NB), 256, 0, stream>>>(x, Xt);
    conv_mfma<NC, true><<<dim3(18, 6, NB), 256, 0, stream>>>(
        Wq, Xt, b_qkv, nullptr, Qb, Kb, Vb, E, nullptr, 0, nullptr);
    flash3<<<dim3(HW / 64, NB * NH), 256, 0, stream>>>(Qb, Kb, Vb, attT, E);
    conv_mfma<HID, false><<<dim3(18, 4, NB), 256, 0, stream>>>(
        Wo, attT, b_out, out, nullptr, nullptr, nullptr, E,
        ticket, 18 * 4 * NB, out + (size_t)NB * NC * HW);
}

// Round 7
// 237.841 us; speedup vs baseline: 1.5799x; 1.2819x over previous
//
#include <hip/hip_runtime.h>
#include <hip/hip_bf16.h>

#define HW 2304          // 48*48
#define NB 8             // batch
#define NC 256           // input channels
#define HID 128          // heads*dim_head
#define DH 32            // dim_head
#define NH 4             // heads
#define SCALE 0.17677669529663687f   // 1/sqrt(32)
#define LOG2E 1.4426950408889634f
#define LN2   0.6931471805599453f

using bf16x8 = __attribute__((ext_vector_type(8))) short;
using f32x4  = __attribute__((ext_vector_type(4))) float;

__device__ __forceinline__ short f2bf(float f) {   // RNE float->bf16
    unsigned u = __float_as_uint(f);
    u += 0x7FFF + ((u >> 16) & 1);
    return (short)(u >> 16);
}
__device__ __forceinline__ unsigned pk2bf(float a, float b) {  // pack 2 bf16 (RNE)
    union { __hip_bfloat162 h; unsigned u; } cv;
    cv.h = __float22bfloat162_rn(float2{a, b});
    return cv.u;
}
__device__ __forceinline__ void gld16(const void* g, void* l) {  // 16B global->LDS DMA
    __builtin_amdgcn_global_load_lds(
        (const __attribute__((address_space(1))) unsigned*)g,
        (__attribute__((address_space(3))) unsigned*)l, 16, 0, 0);
}

// ---------------------------------------------------------------------------
// Pre-pass: fp32 weights -> bf16.
// ---------------------------------------------------------------------------
__global__ void cvt_w(const float* __restrict__ wq, const float* __restrict__ wo,
                      short* __restrict__ Wq, short* __restrict__ Wo)
{
    const int i = blockIdx.x * 256 + threadIdx.x;
    if (i < 384 * 256) Wq[i] = f2bf(wq[i]);
    if (i < 256 * 128) Wo[i] = f2bf(wo[i]);
}

// ---------------------------------------------------------------------------
// Pre-pass: x [b][256][2304] fp32 -> Xt [b][2304][256] bf16 (LDS transpose).
// ---------------------------------------------------------------------------
__global__ __launch_bounds__(256)
void xpose_cvt(const float* __restrict__ x, short* __restrict__ Xt)
{
    __shared__ float T[32][33];
    const int b = blockIdx.z, c0 = blockIdx.y * 32, s0 = blockIdx.x * 32;
    const int ts = threadIdx.x & 31, tc = threadIdx.x >> 5;
    #pragma unroll
    for (int cc = tc; cc < 32; cc += 8)
        T[cc][ts] = x[((size_t)b * NC + c0 + cc) * HW + s0 + ts];
    __syncthreads();
    const int tcc = threadIdx.x & 31, tss = threadIdx.x >> 5;
    #pragma unroll
    for (int ss = tss; ss < 32; ss += 8)
        Xt[((size_t)b * HW + s0 + ss) * NC + c0 + tcc] = f2bf(T[tcc][ss]);
}

// ---------------------------------------------------------------------------
// LDS-free MFMA 1x1-conv GEMM (round-6, unchanged except Q scale):
// Q is pre-scaled by SCALE*LOG2E so flash can use exp2 directly.
// K pair-permuted within 32-key groups; V stored [bh][dh][s].
// ---------------------------------------------------------------------------
template<int KD, bool QKV>
__global__ __launch_bounds__(256, 4)
void conv_mfma(const short* __restrict__ A, const short* __restrict__ Bt,
               const float* __restrict__ bias, float* __restrict__ out0,
               short* __restrict__ Qb, short* __restrict__ Kb,
               short* __restrict__ Vb, float* __restrict__ E,
               int* __restrict__ ticket, int nblocks, float* __restrict__ edst)
{
    const int b  = blockIdx.z;
    const int bm = blockIdx.y * 64;
    const int bn = blockIdx.x * 128;
    const int t  = threadIdx.x;
    const int w  = t >> 6, lane = t & 63;
    const int n16 = lane & 15, quad = lane >> 4;

    __shared__ float red[4];

    const short* Ag  = A + (size_t)(bm + n16) * KD + quad * 8;
    const short* Bg0 = Bt + ((size_t)b * HW + bn + (w * 2 + 0) * 16 + n16) * KD + quad * 8;
    const short* Bg1 = Bt + ((size_t)b * HW + bn + (w * 2 + 1) * 16 + n16) * KD + quad * 8;

    f32x4 acc[4][2] = {};

    for (int kc = 0; kc < KD; kc += 32) {
        bf16x8 am[4], bq[2];
        #pragma unroll
        for (int tm = 0; tm < 4; ++tm)
            am[tm] = *(const bf16x8*)(Ag + (size_t)tm * 16 * KD + kc);
        bq[0] = *(const bf16x8*)(Bg0 + kc);
        bq[1] = *(const bf16x8*)(Bg1 + kc);
        #pragma unroll
        for (int tm = 0; tm < 4; ++tm)
            #pragma unroll
            for (int j = 0; j < 2; ++j)
                acc[tm][j] = __builtin_amdgcn_mfma_f32_16x16x32_bf16(am[tm], bq[j], acc[tm][j], 0, 0, 0);
    }

    float e = 0.f;
    #pragma unroll
    for (int tm = 0; tm < 4; ++tm) {
        const int o0 = bm + tm * 16 + quad * 4;
        const float4 bb = *(const float4*)(bias + o0);
        #pragma unroll
        for (int j = 0; j < 2; ++j) {
            const int s = bn + (w * 2 + j) * 16 + n16;
            float v[4] = {acc[tm][j][0] + bb.x, acc[tm][j][1] + bb.y,
                          acc[tm][j][2] + bb.z, acc[tm][j][3] + bb.w};
            e -= 0.5f * (v[0]*v[0] + v[1]*v[1] + v[2]*v[2] + v[3]*v[3]);
            if (QKV) {
                if (o0 < HID) {                       // Q: scaled by SCALE*log2e
                    const int h = o0 >> 5, dh0 = o0 & 31;
                    const float qs = SCALE * LOG2E;
                    short4 pk = {f2bf(v[0]*qs), f2bf(v[1]*qs),
                                 f2bf(v[2]*qs), f2bf(v[3]*qs)};
                    *(short4*)(Qb + ((size_t)(b * NH + h) * HW + s) * DH + dh0) = pk;
                } else if (o0 < 2 * HID) {            // K: pair-permuted rows
                    const int c = o0 - HID, h = c >> 5, dh0 = c & 31;
                    const int g = s & 31;
                    const int sp = (s & ~31) | ((g & 1) << 4) | (g >> 1);
                    short4 pk = {f2bf(v[0]), f2bf(v[1]), f2bf(v[2]), f2bf(v[3])};
                    *(short4*)(Kb + ((size_t)(b * NH + h) * HW + sp) * DH + dh0) = pk;
                } else {                              // V: [bh][dh][s]
                    const int c = o0 - 2 * HID, h = c >> 5, dh0 = c & 31;
                    #pragma unroll
                    for (int r = 0; r < 4; ++r)
                        Vb[((size_t)(b * NH + h) * DH + dh0 + r) * HW + s] = f2bf(v[r]);
                }
            } else {
                #pragma unroll
                for (int r = 0; r < 4; ++r)
                    out0[((size_t)b * NC + o0 + r) * HW + s] = v[r];
            }
        }
    }

    #pragma unroll
    for (int off = 32; off > 0; off >>= 1) e += __shfl_down(e, off);
    if (lane == 0) red[w] = e;
    __syncthreads();
    if (t == 0) {
        atomicAdd(E, red[0] + red[1] + red[2] + red[3]);
        if (!QKV) {
            __threadfence();
            const int prev = atomicAdd(ticket, 1);
            if (prev == nblocks - 1) {
                __threadfence();
                edst[0] = atomicAdd(E, 0.f);
            }
        }
    }
}

// ---------------------------------------------------------------------------
// Flash attention v4. Block = 64 queries x 4 waves; wave w owns key-quarter
// [w*576, (w+1)*576), ALL 64 queries (16 MFMA / 32-key chunk). K/V chunks are
// DMA'd (global_load_lds, 16B) into wave-private double buffers; loop-top
// `s_waitcnt vmcnt(0)` gives exact 1-chunk pipelining with no barrier.
// XOR swizzle on the DMA's *global* side makes all ds_read_b128 frags <=2-way.
// m=0 fixed shift: cross-wave merge is a pure add via LDS scratch (2 barriers).
// exp2 path: Q pre-scaled by log2e, T rescaled by ln2 at the end.
// ---------------------------------------------------------------------------
__global__ __launch_bounds__(256)
void flash4(const short* __restrict__ Qb, const short* __restrict__ Kb,
            const short* __restrict__ Vb, short* __restrict__ attT,
            float* __restrict__ E)
{
    __shared__ __align__(16) char smem[52224];
    // [0,32768): KV bufs, per wave 8KB: parity p at w*8192+p*4096 (K 2KB | V 2KB)
    // [32768,51200): P tiles, per wave 64x36 shorts
    // after loop: merge scratch, waves 1..3 at (w-1)*17408 + lane*272 (68 floats)

    const int bh   = blockIdx.y;
    const int w    = threadIdx.x >> 6;
    const int lane = threadIdx.x & 63;
    const int n16  = lane & 15, quad = lane >> 4;
    const int qb   = blockIdx.x * 64;

    short* KVw = (short*)smem + w * 4096;             // shorts (8KB per wave)
    short* Pw  = (short*)(smem + 32768) + w * 2304;   // 64x36 shorts
    unsigned* Pw32 = (unsigned*)Pw;

    bf16x8 aq[4];
    #pragma unroll
    for (int qg = 0; qg < 4; ++qg)
        aq[qg] = *(const bf16x8*)(Qb + ((size_t)bh * HW + qb + qg * 16 + n16) * DH + quad * 8);

    // per-lane DMA global byte offsets (XOR-swizzled block mapping)
    const int rL = lane >> 2, cL = (lane & 3) ^ (rL & 3);
    const char* kg = (const char*)(Kb + ((size_t)bh * HW + w * 576) * DH);
    const char* vg = (const char*)(Vb + (size_t)bh * DH * HW + w * 576);
    const int kOffA = rL * 64 + cL * 16,        kOffB = 1024 + rL * 64 + cL * 16;
    const int vOffA = rL * (HW * 2) + cL * 16,  vOffB = 16 * (HW * 2) + rL * (HW * 2) + cL * 16;

    auto issue = [&](int c, int pb) {
        short* lk = KVw + pb * 2048;
        const char* kc = kg + (size_t)c * 2048;   // 32 keys * 64B
        const char* vc = vg + (size_t)c * 64;     // 32 keys * 2B per dh-row
        gld16(kc + kOffA, lk);
        gld16(kc + kOffB, lk + 512);
        gld16(vc + vOffA, lk + 1024);
        gld16(vc + vOffB, lk + 1536);
    };

    f32x4 acc[4][2] = {};
    float ls2[4][4] = {}, ts2[4][4] = {};

    issue(0, 0);                                  // preload chunk 0
    const int sw = (quad ^ (n16 & 3)) * 8;        // frag-read swizzle (shorts)

    for (int c = 0; c < 18; ++c) {
        const int pb = c & 1;
        asm volatile("s_waitcnt vmcnt(0)" ::: "memory");
        if (c + 1 < 18) issue(c + 1, pb ^ 1);

        const short* lk = KVw + pb * 2048;
        const bf16x8 bk0 = *(const bf16x8*)(lk + n16 * 32 + sw);          // keys (perm) 0-15
        const bf16x8 bk1 = *(const bf16x8*)(lk + 512  + n16 * 32 + sw);   // keys (perm) 16-31
        const bf16x8 bv0 = *(const bf16x8*)(lk + 1024 + n16 * 32 + sw);   // dh 0-15
        const bf16x8 bv1 = *(const bf16x8*)(lk + 1536 + n16 * 32 + sw);   // dh 16-31

        #pragma unroll
        for (int qg = 0; qg < 4; ++qg) {
            f32x4 z = {};
            const f32x4 s0 = __builtin_amdgcn_mfma_f32_16x16x32_bf16(aq[qg], bk0, z, 0, 0, 0);
            const f32x4 s1 = __builtin_amdgcn_mfma_f32_16x16x32_bf16(aq[qg], bk1, z, 0, 0, 0);
            #pragma unroll
            for (int r = 0; r < 4; ++r) {
                const float p0 = exp2f(s0[r]);    // key 2*n16   (pair-permuted K)
                const float p1 = exp2f(s1[r]);    // key 2*n16+1
                ls2[qg][r] += p0 + p1;
                ts2[qg][r] += p0 * s0[r] + p1 * s1[r];
                Pw32[(qg * 16 + quad * 4 + r) * 18 + n16] = pk2bf(p0, p1);
            }
        }
        #pragma unroll
        for (int qg = 0; qg < 4; ++qg) {
            const bf16x8 pa = *(const bf16x8*)(Pw + (qg * 16 + n16) * 36 + quad * 8);
            acc[qg][0] = __builtin_amdgcn_mfma_f32_16x16x32_bf16(pa, bv0, acc[qg][0], 0, 0, 0);
            acc[qg][1] = __builtin_amdgcn_mfma_f32_16x16x32_bf16(pa, bv1, acc[qg][1], 0, 0, 0);
        }
    }

    __syncthreads();                               // all waves done with KV/P
    if (w > 0) {                                   // publish partials
        float* mp = (float*)(smem + (size_t)(w - 1) * 17408) + (size_t)lane * 68;
        #pragma unroll
        for (int qg = 0; qg < 4; ++qg) {
            *(f32x4*)(mp + (qg * 2 + 0) * 4) = acc[qg][0];
            *(f32x4*)(mp + (qg * 2 + 1) * 4) = acc[qg][1];
            *(f32x4*)(mp + 32 + qg * 4) = *(const f32x4*)ls2[qg];
            *(f32x4*)(mp + 48 + qg * 4) = *(const f32x4*)ts2[qg];
        }
    }
    __syncthreads();
    if (w == 0) {
        #pragma unroll
        for (int ww = 0; ww < 3; ++ww) {
            const float* mp = (const float*)(smem + (size_t)ww * 17408) + (size_t)lane * 68;
            #pragma unroll
            for (int qg = 0; qg < 4; ++qg) {
                acc[qg][0] += *(const f32x4*)(mp + (qg * 2 + 0) * 4);
                acc[qg][1] += *(const f32x4*)(mp + (qg * 2 + 1) * 4);
                const f32x4 l4 = *(const f32x4*)(mp + 32 + qg * 4);
                const f32x4 t4 = *(const f32x4*)(mp + 48 + qg * 4);
                #pragma unroll
                for (int r = 0; r < 4; ++r) { ls2[qg][r] += l4[r]; ts2[qg][r] += t4[r]; }
            }
        }
        #pragma unroll
        for (int m = 1; m < 16; m <<= 1)
            #pragma unroll
            for (int qg = 0; qg < 4; ++qg)
                #pragma unroll
                for (int r = 0; r < 4; ++r) {
                    ls2[qg][r] += __shfl_xor(ls2[qg][r], m);
                    ts2[qg][r] += __shfl_xor(ts2[qg][r], m);
                }

        const int bb = bh >> 2, h = bh & 3;
        float e = 0.f;
        #pragma unroll
        for (int qg = 0; qg < 4; ++qg)
            #pragma unroll
            for (int r = 0; r < 4; ++r) {
                const int q = qb + qg * 16 + quad * 4 + r;
                const float L = ls2[qg][r];
                const float invl = 1.f / L;
                short* ap = attT + ((size_t)bb * HW + q) * HID + h * 32;
                ap[n16]      = f2bf(acc[qg][0][r] * invl);
                ap[n16 + 16] = f2bf(acc[qg][1][r] * invl);
                e += (LN2 * ts2[qg][r]) * invl - __logf(L);
            }
        e = (n16 == 0) ? e : 0.f;
        e += __shfl_xor(e, 16);
        e += __shfl_xor(e, 32);
        if (lane == 0) atomicAdd(E, e);
    }
}

// ---------------------------------------------------------------------------
extern "C" void kernel_launch(void* const* d_in, const int* in_sizes, int n_in,
                              void* d_out, int out_size, void* d_ws, size_t ws_size,
                              hipStream_t stream) {
    const float* x     = (const float*)d_in[0];
    const float* w_qkv = (const float*)d_in[1];
    const float* b_qkv = (const float*)d_in[2];
    const float* w_out = (const float*)d_in[3];
    const float* b_out = (const float*)d_in[4];
    float* out = (float*)d_out;

    float* wsf    = (float*)d_ws;
    float* E      = wsf;                               // [0] energy accumulator
    int*   ticket = (int*)d_ws + 1;                    // [1] conv2 ticket
    short* Xt   = (short*)(wsf + 16);                  // bf16 [b][s][c]
    short* Wq   = Xt + (size_t)NB * HW * NC;           // bf16 [384][256]
    short* Wo   = Wq + 384 * 256;                      // bf16 [256][128]
    short* Qb   = Wo + 256 * 128;                      // bf16 [bh][s][dh] (xSCALE*log2e)
    short* Kb   = Qb + (size_t)NB * NH * HW * DH;      // bf16 [bh][s'][dh], pair-permuted
    short* Vb   = Kb + (size_t)NB * NH * HW * DH;      // bf16 [bh][dh][s]
    short* attT = Vb + (size_t)NB * NH * HW * DH;      // bf16 [b][s][hid]

    (void)hipMemsetAsync(d_ws, 0, 64, stream);

    cvt_w<<<384, 256, 0, stream>>>(w_qkv, w_out, Wq, Wo);
    xpose_cvt<<<dim3(HW / 32, NC / 32, NB), 256, 0, stream>>>(x, Xt);
    conv_mfma<NC, true><<<dim3(18, 6, NB), 256, 0, stream>>>(
        Wq, Xt, b_qkv, nullptr, Qb, Kb, Vb, E, nullptr, 0, nullptr);
    flash4<<<dim3(HW / 64, NB * NH), 256, 0, stream>>>(Qb, Kb, Vb, attT, E);
    conv_mfma<HID, false><<<dim3(18, 4, NB), 256, 0, stream>>>(
        Wo, attT, b_out, out, nullptr, nullptr, nullptr, E,
        ticket, 18 * 4 * NB, out + (size_t)NB * NC * HW);
}

// Round 8
// 228.277 us; speedup vs baseline: 1.6461x; 1.0419x over previous
//
#include <hip/hip_runtime.h>
#include <hip/hip_bf16.h>

#define HW 2304          // 48*48
#define NB 8             // batch
#define NC 256           // input channels
#define HID 128          // heads*dim_head
#define DH 32            // dim_head
#define NH 4             // heads
#define SCALE 0.17677669529663687f   // 1/sqrt(32)
#define LOG2E 1.4426950408889634f
#define LN2   0.6931471805599453f

using bf16x8 = __attribute__((ext_vector_type(8))) short;
using f32x4  = __attribute__((ext_vector_type(4))) float;

__device__ __forceinline__ short f2bf(float f) {   // RNE float->bf16
    unsigned u = __float_as_uint(f);
    u += 0x7FFF + ((u >> 16) & 1);
    return (short)(u >> 16);
}
__device__ __forceinline__ unsigned pk2bf(float a, float b) {  // pack 2 bf16 (RNE)
    union { __hip_bfloat162 h; unsigned u; } cv;
    cv.h = __float22bfloat162_rn(float2{a, b});
    return cv.u;
}
__device__ __forceinline__ void gld16(const void* g, void* l) {  // 16B global->LDS DMA
    __builtin_amdgcn_global_load_lds(
        (const __attribute__((address_space(1))) unsigned*)g,
        (__attribute__((address_space(3))) unsigned*)l, 16, 0, 0);
}

// ---------------------------------------------------------------------------
// Pre-pass: fp32 weights -> bf16.
// ---------------------------------------------------------------------------
__global__ void cvt_w(const float* __restrict__ wq, const float* __restrict__ wo,
                      short* __restrict__ Wq, short* __restrict__ Wo)
{
    const int i = blockIdx.x * 256 + threadIdx.x;
    if (i < 384 * 256) Wq[i] = f2bf(wq[i]);
    if (i < 256 * 128) Wo[i] = f2bf(wo[i]);
}

// ---------------------------------------------------------------------------
// Pre-pass: x [b][256][2304] fp32 -> Xt [b][2304][256] bf16 (LDS transpose).
// ---------------------------------------------------------------------------
__global__ __launch_bounds__(256)
void xpose_cvt(const float* __restrict__ x, short* __restrict__ Xt)
{
    __shared__ float T[32][33];
    const int b = blockIdx.z, c0 = blockIdx.y * 32, s0 = blockIdx.x * 32;
    const int ts = threadIdx.x & 31, tc = threadIdx.x >> 5;
    #pragma unroll
    for (int cc = tc; cc < 32; cc += 8)
        T[cc][ts] = x[((size_t)b * NC + c0 + cc) * HW + s0 + ts];
    __syncthreads();
    const int tcc = threadIdx.x & 31, tss = threadIdx.x >> 5;
    #pragma unroll
    for (int ss = tss; ss < 32; ss += 8)
        Xt[((size_t)b * HW + s0 + ss) * NC + c0 + tcc] = f2bf(T[tcc][ss]);
}

// ---------------------------------------------------------------------------
// LDS-free MFMA 1x1-conv GEMM (unchanged from round 7).
// Q pre-scaled by SCALE*LOG2E; K pair-permuted in 32-key groups; V [bh][dh][s].
// ---------------------------------------------------------------------------
template<int KD, bool QKV>
__global__ __launch_bounds__(256, 4)
void conv_mfma(const short* __restrict__ A, const short* __restrict__ Bt,
               const float* __restrict__ bias, float* __restrict__ out0,
               short* __restrict__ Qb, short* __restrict__ Kb,
               short* __restrict__ Vb, float* __restrict__ E,
               int* __restrict__ ticket, int nblocks, float* __restrict__ edst)
{
    const int b  = blockIdx.z;
    const int bm = blockIdx.y * 64;
    const int bn = blockIdx.x * 128;
    const int t  = threadIdx.x;
    const int w  = t >> 6, lane = t & 63;
    const int n16 = lane & 15, quad = lane >> 4;

    __shared__ float red[4];

    const short* Ag  = A + (size_t)(bm + n16) * KD + quad * 8;
    const short* Bg0 = Bt + ((size_t)b * HW + bn + (w * 2 + 0) * 16 + n16) * KD + quad * 8;
    const short* Bg1 = Bt + ((size_t)b * HW + bn + (w * 2 + 1) * 16 + n16) * KD + quad * 8;

    f32x4 acc[4][2] = {};

    for (int kc = 0; kc < KD; kc += 32) {
        bf16x8 am[4], bq[2];
        #pragma unroll
        for (int tm = 0; tm < 4; ++tm)
            am[tm] = *(const bf16x8*)(Ag + (size_t)tm * 16 * KD + kc);
        bq[0] = *(const bf16x8*)(Bg0 + kc);
        bq[1] = *(const bf16x8*)(Bg1 + kc);
        #pragma unroll
        for (int tm = 0; tm < 4; ++tm)
            #pragma unroll
            for (int j = 0; j < 2; ++j)
                acc[tm][j] = __builtin_amdgcn_mfma_f32_16x16x32_bf16(am[tm], bq[j], acc[tm][j], 0, 0, 0);
    }

    float e = 0.f;
    #pragma unroll
    for (int tm = 0; tm < 4; ++tm) {
        const int o0 = bm + tm * 16 + quad * 4;
        const float4 bb = *(const float4*)(bias + o0);
        #pragma unroll
        for (int j = 0; j < 2; ++j) {
            const int s = bn + (w * 2 + j) * 16 + n16;
            float v[4] = {acc[tm][j][0] + bb.x, acc[tm][j][1] + bb.y,
                          acc[tm][j][2] + bb.z, acc[tm][j][3] + bb.w};
            e -= 0.5f * (v[0]*v[0] + v[1]*v[1] + v[2]*v[2] + v[3]*v[3]);
            if (QKV) {
                if (o0 < HID) {                       // Q: scaled by SCALE*log2e
                    const int h = o0 >> 5, dh0 = o0 & 31;
                    const float qs = SCALE * LOG2E;
                    short4 pk = {f2bf(v[0]*qs), f2bf(v[1]*qs),
                                 f2bf(v[2]*qs), f2bf(v[3]*qs)};
                    *(short4*)(Qb + ((size_t)(b * NH + h) * HW + s) * DH + dh0) = pk;
                } else if (o0 < 2 * HID) {            // K: pair-permuted rows
                    const int c = o0 - HID, h = c >> 5, dh0 = c & 31;
                    const int g = s & 31;
                    const int sp = (s & ~31) | ((g & 1) << 4) | (g >> 1);
                    short4 pk = {f2bf(v[0]), f2bf(v[1]), f2bf(v[2]), f2bf(v[3])};
                    *(short4*)(Kb + ((size_t)(b * NH + h) * HW + sp) * DH + dh0) = pk;
                } else {                              // V: [bh][dh][s]
                    const int c = o0 - 2 * HID, h = c >> 5, dh0 = c & 31;
                    #pragma unroll
                    for (int r = 0; r < 4; ++r)
                        Vb[((size_t)(b * NH + h) * DH + dh0 + r) * HW + s] = f2bf(v[r]);
                }
            } else {
                #pragma unroll
                for (int r = 0; r < 4; ++r)
                    out0[((size_t)b * NC + o0 + r) * HW + s] = v[r];
            }
        }
    }

    #pragma unroll
    for (int off = 32; off > 0; off >>= 1) e += __shfl_down(e, off);
    if (lane == 0) red[w] = e;
    __syncthreads();
    if (t == 0) {
        atomicAdd(E, red[0] + red[1] + red[2] + red[3]);
        if (!QKV) {
            __threadfence();
            const int prev = atomicAdd(ticket, 1);
            if (prev == nblocks - 1) {
                __threadfence();
                edst[0] = atomicAdd(E, 0.f);
            }
        }
    }
}

// ---------------------------------------------------------------------------
// Flash attention v5 (m97-style shared-KV K-loop). Block = 128 queries x 4
// waves; wave w owns queries [qb+32w, qb+32w+32) and walks ALL 2304 keys.
// Per 32-key chunk: one shared 4KB K/V buffer (K 2KB | V 2KB), DMA'd by all
// 256 threads (1 gld16 each, XOR-swizzled global->LDS block permutation so
// frag reads are conflict-free), double-buffered with ONE barrier per chunk
// (syncthreads' vmcnt(0) drain = the DMA completion wait). No cross-wave
// merge. m=0 fixed shift; raw v_exp_f32 (|s| <= ~1). P stride 40 shorts
// (16B-aligned b128 rows). attT out: bf16 [b][s][hid].
// ---------------------------------------------------------------------------
__global__ __launch_bounds__(256)
void flash5(const short* __restrict__ Qb, const short* __restrict__ Kb,
            const short* __restrict__ Vb, short* __restrict__ attT,
            float* __restrict__ E)
{
    __shared__ __align__(16) char smem[8192 + 4 * 2560];
    // [0,8192): KV double buffer (4KB each: K 2KB | V 2KB)
    // [8192,+): per-wave P tile, 32 rows x 40 shorts

    const int bh   = blockIdx.y;
    const int w    = threadIdx.x >> 6;
    const int lane = threadIdx.x & 63;
    const int n16  = lane & 15, quad = lane >> 4;
    const int qb   = blockIdx.x * 128 + w * 32;

    short* Pw = (short*)(smem + 8192) + w * 1280;
    unsigned* Pw32 = (unsigned*)Pw;

    bf16x8 aq[2];
    #pragma unroll
    for (int qg = 0; qg < 2; ++qg)
        aq[qg] = *(const bf16x8*)(Qb + ((size_t)bh * HW + qb + qg * 16 + n16) * DH + quad * 8);

    // DMA role: waves 0,1 -> K halves; waves 2,3 -> V halves.
    // Lane L=(rL,cL): fetch global block (row rL, chunk cL^(rL&3)), deposit at L*16.
    const int rL = lane >> 2, cL = (lane & 3) ^ (rL & 3);
    const int whalf = w & 1;
    const char* gbase;
    size_t gstep;
    if (w < 2) {
        gbase = (const char*)(Kb + (size_t)bh * HW * DH) + (whalf * 16 + rL) * 64 + cL * 16;
        gstep = 2048;                      // 32 keys * 64 B
    } else {
        gbase = (const char*)(Vb + (size_t)bh * DH * HW)
              + (size_t)(whalf * 16 + rL) * (HW * 2) + cL * 16;
        gstep = 64;                        // 32 keys * 2 B per dh-row
    }

    gld16(gbase, smem + w * 1024);         // preload chunk 0 -> buf 0

    f32x4 acc[2][2] = {};
    float ls[2][4] = {}, ts[2][4] = {};
    const int swz = (quad ^ (n16 & 3)) * 8;   // frag-read XOR swizzle (shorts)

    for (int c = 0; c < 72; ++c) {
        __syncthreads();                   // waits vmcnt(0): chunk c's DMA landed
        if (c + 1 < 72)
            gld16(gbase + (size_t)(c + 1) * gstep, smem + ((c + 1) & 1) * 4096 + w * 1024);

        const short* kb = (const short*)(smem + (c & 1) * 4096);
        const bf16x8 bk0 = *(const bf16x8*)(kb + n16 * 32 + swz);          // keys(perm) 0-15
        const bf16x8 bk1 = *(const bf16x8*)(kb + 512  + n16 * 32 + swz);   // keys(perm) 16-31
        const bf16x8 bv0 = *(const bf16x8*)(kb + 1024 + n16 * 32 + swz);   // dh 0-15
        const bf16x8 bv1 = *(const bf16x8*)(kb + 1536 + n16 * 32 + swz);   // dh 16-31

        #pragma unroll
        for (int qg = 0; qg < 2; ++qg) {
            f32x4 z = {};
            const f32x4 s0 = __builtin_amdgcn_mfma_f32_16x16x32_bf16(aq[qg], bk0, z, 0, 0, 0);
            const f32x4 s1 = __builtin_amdgcn_mfma_f32_16x16x32_bf16(aq[qg], bk1, z, 0, 0, 0);
            #pragma unroll
            for (int r = 0; r < 4; ++r) {
                const float p0 = __builtin_amdgcn_exp2f(s0[r]);   // key 2*n16
                const float p1 = __builtin_amdgcn_exp2f(s1[r]);   // key 2*n16+1
                ls[qg][r] += p0 + p1;
                ts[qg][r] += p0 * s0[r] + p1 * s1[r];
                Pw32[(qg * 16 + quad * 4 + r) * 20 + n16] = pk2bf(p0, p1);
            }
        }
        #pragma unroll
        for (int qg = 0; qg < 2; ++qg) {
            const bf16x8 pa = *(const bf16x8*)(Pw + (qg * 16 + n16) * 40 + quad * 8);
            acc[qg][0] = __builtin_amdgcn_mfma_f32_16x16x32_bf16(pa, bv0, acc[qg][0], 0, 0, 0);
            acc[qg][1] = __builtin_amdgcn_mfma_f32_16x16x32_bf16(pa, bv1, acc[qg][1], 0, 0, 0);
        }
    }

    // reduce ls/ts across the 16 lanes (key dim) of each quad group
    #pragma unroll
    for (int m = 1; m < 16; m <<= 1)
        #pragma unroll
        for (int qg = 0; qg < 2; ++qg)
            #pragma unroll
            for (int r = 0; r < 4; ++r) {
                ls[qg][r] += __shfl_xor(ls[qg][r], m);
                ts[qg][r] += __shfl_xor(ts[qg][r], m);
            }

    const int bb = bh >> 2, h = bh & 3;
    float e = 0.f;
    #pragma unroll
    for (int qg = 0; qg < 2; ++qg)
        #pragma unroll
        for (int r = 0; r < 4; ++r) {
            const int q = qb + qg * 16 + quad * 4 + r;
            const float L = ls[qg][r];
            const float invl = 1.f / L;
            short* ap = attT + ((size_t)bb * HW + q) * HID + h * 32;
            ap[n16]      = f2bf(acc[qg][0][r] * invl);
            ap[n16 + 16] = f2bf(acc[qg][1][r] * invl);
            e += (LN2 * ts[qg][r]) * invl - __logf(L);
        }
    e = (n16 == 0) ? e : 0.f;
    e += __shfl_xor(e, 16);
    e += __shfl_xor(e, 32);
    if (lane == 0) atomicAdd(E, e);        // 4 atomics/block
}

// ---------------------------------------------------------------------------
extern "C" void kernel_launch(void* const* d_in, const int* in_sizes, int n_in,
                              void* d_out, int out_size, void* d_ws, size_t ws_size,
                              hipStream_t stream) {
    const float* x     = (const float*)d_in[0];
    const float* w_qkv = (const float*)d_in[1];
    const float* b_qkv = (const float*)d_in[2];
    const float* w_out = (const float*)d_in[3];
    const float* b_out = (const float*)d_in[4];
    float* out = (float*)d_out;

    float* wsf    = (float*)d_ws;
    float* E      = wsf;                               // [0] energy accumulator
    int*   ticket = (int*)d_ws + 1;                    // [1] conv2 ticket
    short* Xt   = (short*)(wsf + 16);                  // bf16 [b][s][c]
    short* Wq   = Xt + (size_t)NB * HW * NC;           // bf16 [384][256]
    short* Wo   = Wq + 384 * 256;                      // bf16 [256][128]
    short* Qb   = Wo + 256 * 128;                      // bf16 [bh][s][dh] (xSCALE*log2e)
    short* Kb   = Qb + (size_t)NB * NH * HW * DH;      // bf16 [bh][s'][dh], pair-permuted
    short* Vb   = Kb + (size_t)NB * NH * HW * DH;      // bf16 [bh][dh][s]
    short* attT = Vb + (size_t)NB * NH * HW * DH;      // bf16 [b][s][hid]

    (void)hipMemsetAsync(d_ws, 0, 64, stream);

    cvt_w<<<384, 256, 0, stream>>>(w_qkv, w_out, Wq, Wo);
    xpose_cvt<<<dim3(HW / 32, NC / 32, NB), 256, 0, stream>>>(x, Xt);
    conv_mfma<NC, true><<<dim3(18, 6, NB), 256, 0, stream>>>(
        Wq, Xt, b_qkv, nullptr, Qb, Kb, Vb, E, nullptr, 0, nullptr);
    flash5<<<dim3(HW / 128, NB * NH), 256, 0, stream>>>(Qb, Kb, Vb, attT, E);
    conv_mfma<HID, false><<<dim3(18, 4, NB), 256, 0, stream>>>(
        Wo, attT, b_out, out, nullptr, nullptr, nullptr, E,
        ticket, 18 * 4 * NB, out + (size_t)NB * NC * HW);
}